// Round 1
// baseline (2387.616 us; speedup 1.0000x reference)
//
#include <hip/hip_runtime.h>
#include <math.h>

// Problem constants (B,S,D,H,F = 4,2048,512,8,2048)
constexpr int B = 4, S = 2048, D = 512, H = 8, HD = 64, F = 2048;
constexpr int M = B * S;              // 8192 token rows
constexpr float SCALE = 0.125f;       // HD^-0.5

// ---------------------------------------------------------------- GEMM
// C[M,N] = A[M,K] @ W[K,N] + bias[N], optional exact GELU epilogue.
// BM=BN=64, BK=16, 256 threads, 4x4 outputs/thread.
template<int GELU>
__global__ __launch_bounds__(256)
void gemm_bias(const float* __restrict__ A, const float* __restrict__ W,
               const float* __restrict__ bias, float* __restrict__ C,
               int K, int N) {
  // As transposed [k][m], padded to 68 so rows stay 16B-aligned (b128 reads)
  // and scalar writes are <=2-way bank conflicted (free per m136).
  __shared__ float As[16][68];
  __shared__ float Bs[16][64];
  const int t  = threadIdx.x;
  const int tx = t & 15, ty = t >> 4;
  const int m0 = blockIdx.y * 64, n0 = blockIdx.x * 64;
  const int la_m = t >> 2, la_k = (t & 3) << 2;   // A tile: 64 rows x 16 cols
  const int lb_k = t >> 4, lb_n = (t & 15) << 2;  // B tile: 16 rows x 64 cols
  float acc[4][4] = {};
  for (int k0 = 0; k0 < K; k0 += 16) {
    float4 av = *(const float4*)&A[(size_t)(m0 + la_m) * K + (k0 + la_k)];
    float4 bv = *(const float4*)&W[(size_t)(k0 + lb_k) * N + (n0 + lb_n)];
    As[la_k + 0][la_m] = av.x;
    As[la_k + 1][la_m] = av.y;
    As[la_k + 2][la_m] = av.z;
    As[la_k + 3][la_m] = av.w;
    *(float4*)&Bs[lb_k][lb_n] = bv;
    __syncthreads();
#pragma unroll
    for (int k = 0; k < 16; ++k) {
      float a[4], b[4];
#pragma unroll
      for (int i = 0; i < 4; ++i) a[i] = As[k][ty * 4 + i];
#pragma unroll
      for (int j = 0; j < 4; ++j) b[j] = Bs[k][tx * 4 + j];
#pragma unroll
      for (int i = 0; i < 4; ++i)
#pragma unroll
        for (int j = 0; j < 4; ++j)
          acc[i][j] = fmaf(a[i], b[j], acc[i][j]);
    }
    __syncthreads();
  }
#pragma unroll
  for (int i = 0; i < 4; ++i) {
    float vv[4];
#pragma unroll
    for (int j = 0; j < 4; ++j) {
      float v = acc[i][j] + bias[n0 + tx * 4 + j];
      if (GELU) v = 0.5f * v * (1.0f + erff(v * 0.70710678118654752f));
      vv[j] = v;
    }
    *(float4*)&C[(size_t)(m0 + ty * 4 + i) * N + (n0 + tx * 4)] =
        make_float4(vv[0], vv[1], vv[2], vv[3]);
  }
}

// ---------------------------------------------------------------- Attention
// Flash-style: block = (32 q-rows) x (one b,h). K/V tiles of 32 in LDS,
// online softmax (m,l per row). qkv layout: [M, 3D], q|k|v segments,
// head h at cols h*HD within each segment.
__global__ __launch_bounds__(256)
void attn(const float* __restrict__ qkv, float* __restrict__ out) {
  const int bh = blockIdx.y;
  const int b = bh / H, h = bh % H;
  const int q0 = blockIdx.x * 32;
  const size_t base = (size_t)b * S * (3 * D);
  const float* qb = qkv + base + h * HD;
  const float* kb = qkv + base + D + h * HD;
  const float* vb = qkv + base + 2 * D + h * HD;

  __shared__ float q_s[32][HD + 1];   // +1 pad: stride 65 -> conflict-free dot reads
  __shared__ float k_s[32][HD + 1];
  __shared__ float v_s[32][HD + 1];
  __shared__ float s_s[32][33];       // +1 pad breaks 8-way conflict on P reads
  __shared__ float r_scale[32], r_l[32], r_m[32];

  const int t = threadIdx.x;
  for (int i = t; i < 512; i += 256) {          // 32x64 Q tile, float4 global loads
    int r = i >> 4, c = (i & 15) << 2;
    float4 v4 = *(const float4*)&qb[(size_t)(q0 + r) * (3 * D) + c];
    q_s[r][c] = v4.x; q_s[r][c + 1] = v4.y; q_s[r][c + 2] = v4.z; q_s[r][c + 3] = v4.w;
  }
  if (t < 32) { r_m[t] = -1e30f; r_l[t] = 0.0f; }

  float o[8];
#pragma unroll
  for (int j = 0; j < 8; ++j) o[j] = 0.0f;
  const int r  = t >> 3;          // PV: thread owns row r, cols cb..cb+7
  const int cb = (t & 7) << 3;
  const int sr = t >> 3;          // S:  thread computes row sr, cols sc..sc+3
  const int sc = (t & 7) << 2;

  for (int kt = 0; kt < S; kt += 32) {
    __syncthreads();              // protect k_s/v_s/s_s from previous iter readers
    for (int i = t; i < 512; i += 256) {
      int rr = i >> 4, c = (i & 15) << 2;
      float4 k4 = *(const float4*)&kb[(size_t)(kt + rr) * (3 * D) + c];
      k_s[rr][c] = k4.x; k_s[rr][c + 1] = k4.y; k_s[rr][c + 2] = k4.z; k_s[rr][c + 3] = k4.w;
      float4 v4 = *(const float4*)&vb[(size_t)(kt + rr) * (3 * D) + c];
      v_s[rr][c] = v4.x; v_s[rr][c + 1] = v4.y; v_s[rr][c + 2] = v4.z; v_s[rr][c + 3] = v4.w;
    }
    __syncthreads();
    // S tile = Q K^T * scale  (4 dots of length 64 per thread)
    {
      float sa[4] = {0.f, 0.f, 0.f, 0.f};
#pragma unroll
      for (int d = 0; d < HD; ++d) {
        float qv = q_s[sr][d];
#pragma unroll
        for (int j = 0; j < 4; ++j) sa[j] = fmaf(qv, k_s[sc + j][d], sa[j]);
      }
#pragma unroll
      for (int j = 0; j < 4; ++j) s_s[sr][sc + j] = sa[j] * SCALE;
    }
    __syncthreads();
    // online softmax update, one thread per row (known round-0 inefficiency)
    if (t < 32) {
      float m_old = r_m[t];
      float mt = m_old;
#pragma unroll
      for (int c = 0; c < 32; ++c) mt = fmaxf(mt, s_s[t][c]);
      float sum = 0.0f;
      for (int c = 0; c < 32; ++c) {
        float p = expf(s_s[t][c] - mt);
        s_s[t][c] = p;
        sum += p;
      }
      float sc0 = expf(m_old - mt);
      r_scale[t] = sc0;
      r_m[t] = mt;
      r_l[t] = r_l[t] * sc0 + sum;
    }
    __syncthreads();
    float rs = r_scale[r];
#pragma unroll
    for (int j = 0; j < 8; ++j) o[j] *= rs;
#pragma unroll
    for (int kk = 0; kk < 32; ++kk) {
      float p = s_s[r][kk];
#pragma unroll
      for (int j = 0; j < 8; ++j) o[j] = fmaf(p, v_s[kk][cb + j], o[j]);
    }
  }
  __syncthreads();
  float inv = 1.0f / r_l[r];
#pragma unroll
  for (int j = 0; j < 8; ++j) o[j] *= inv;
  // merged-head layout: out[b, s, h*HD + c]
  float* op = out + (size_t)(b * S + q0 + r) * D + h * HD + cb;
  *(float4*)&op[0] = make_float4(o[0], o[1], o[2], o[3]);
  *(float4*)&op[4] = make_float4(o[4], o[5], o[6], o[7]);
}

// ---------------------------------------------------------------- Add + LayerNorm
// out[row] = LN(a[row] + res[row]) * g + be ; one 256-thr block per row (D=512)
__global__ __launch_bounds__(256)
void add_ln(const float* __restrict__ a, const float* __restrict__ res,
            const float* __restrict__ g, const float* __restrict__ be,
            float* __restrict__ out) {
  const int row = blockIdx.x;
  const int t = threadIdx.x;
  const size_t off = (size_t)row * D;
  float x0 = a[off + t] + res[off + t];
  float x1 = a[off + t + 256] + res[off + t + 256];
  float sum = x0 + x1;
  float sq  = x0 * x0 + x1 * x1;
#pragma unroll
  for (int o2 = 32; o2 > 0; o2 >>= 1) {
    sum += __shfl_down(sum, o2);
    sq  += __shfl_down(sq, o2);
  }
  __shared__ float ssum[4], ssq[4];
  const int wid = t >> 6;
  if ((t & 63) == 0) { ssum[wid] = sum; ssq[wid] = sq; }
  __syncthreads();
  if (t == 0) {
    ssum[0] = ssum[0] + ssum[1] + ssum[2] + ssum[3];
    ssq[0]  = ssq[0] + ssq[1] + ssq[2] + ssq[3];
  }
  __syncthreads();
  float mu   = ssum[0] * (1.0f / D);
  float var  = ssq[0] * (1.0f / D) - mu * mu;   // biased var, matches jnp.var
  float rstd = rsqrtf(var + 1e-5f);
  out[off + t]       = (x0 - mu) * rstd * g[t] + be[t];
  out[off + t + 256] = (x1 - mu) * rstd * g[t + 256] + be[t + 256];
}

// ---------------------------------------------------------------- launch
extern "C" void kernel_launch(void* const* d_in, const int* in_sizes, int n_in,
                              void* d_out, int out_size, void* d_ws, size_t ws_size,
                              hipStream_t stream) {
  const float* x     = (const float*)d_in[0];
  const float* w_qkv = (const float*)d_in[1];
  const float* b_qkv = (const float*)d_in[2];
  const float* w_o   = (const float*)d_in[3];
  const float* b_o   = (const float*)d_in[4];
  const float* w1    = (const float*)d_in[5];
  const float* b1    = (const float*)d_in[6];
  const float* w2    = (const float*)d_in[7];
  const float* b2    = (const float*)d_in[8];
  const float* g1    = (const float*)d_in[9];
  const float* be1   = (const float*)d_in[10];
  const float* g2    = (const float*)d_in[11];
  const float* be2   = (const float*)d_in[12];
  float* out = (float*)d_out;

  // Workspace layout (floats). Region 0 sized for the larger of qkv [M,3D]
  // and ffn hidden [M,F] (qkv is dead before ffn_h is written).
  float* ws     = (float*)d_ws;
  float* qkv    = ws;                            // [M, 3D] = 50.3 MB
  float* ffn_h  = ws;                            // [M, F]  = 67 MB (reuse)
  float* attn_o = ws + (size_t)M * F;            // [M, D]
  float* buf    = attn_o + (size_t)M * D;        // o-proj out, then ffn2 out
  float* ln1    = buf + (size_t)M * D;           // [M, D] (ffn input + residual 2)
  // total: (M*F + 3*M*D)*4 = 117.4 MB

  gemm_bias<0><<<dim3((3 * D) / 64, M / 64), 256, 0, stream>>>(x, w_qkv, b_qkv, qkv, D, 3 * D);
  attn<<<dim3(S / 32, B * H), 256, 0, stream>>>(qkv, attn_o);
  gemm_bias<0><<<dim3(D / 64, M / 64), 256, 0, stream>>>(attn_o, w_o, b_o, buf, D, D);
  add_ln<<<M, 256, 0, stream>>>(buf, x, g1, be1, ln1);
  gemm_bias<1><<<dim3(F / 64, M / 64), 256, 0, stream>>>(ln1, w1, b1, ffn_h, D, F);
  gemm_bias<0><<<dim3(D / 64, M / 64), 256, 0, stream>>>(ffn_h, w2, b2, buf, F, D);
  add_ln<<<M, 256, 0, stream>>>(buf, ln1, g2, be2, out);
}

// Round 2
// 363.997 us; speedup vs baseline: 6.5594x; 6.5594x over previous
//
#include <hip/hip_runtime.h>
#include <math.h>

// Problem constants (B,S,D,H,F = 4,2048,512,8,2048)
constexpr int B = 4, S = 2048, D = 512, H = 8, HD = 64, F = 2048;
constexpr int M = B * S;                      // 8192 token rows
constexpr float C_QK = 0.125f * 1.44269504088896340736f;  // SCALE * log2(e)

typedef __bf16 bf16x8 __attribute__((ext_vector_type(8)));
typedef float  f32x4  __attribute__((ext_vector_type(4)));

static __device__ __forceinline__ short f2bf(float f) {
  return __builtin_bit_cast(short, (__bf16)f);   // RNE via fptrunc
}

static __device__ __forceinline__ void gload16(const void* g, void* l) {
  __builtin_amdgcn_global_load_lds(
      (const __attribute__((address_space(1))) unsigned int*)g,
      (__attribute__((address_space(3))) unsigned int*)l, 16, 0, 0);
}

// ---------------------------------------------------------------- prep
// fp32 -> bf16 row-major cast (x). 4 elems/thread, exact-size grid.
__global__ __launch_bounds__(256)
void cast_x(const float4* __restrict__ in, short4* __restrict__ out) {
  int i = blockIdx.x * 256 + threadIdx.x;
  float4 v = in[i];
  out[i] = make_short4(f2bf(v.x), f2bf(v.y), f2bf(v.z), f2bf(v.w));
}

// fp32 [R][C] -> bf16 [C][R] transpose-cast (weights -> W^T for GEMM B-op).
__global__ __launch_bounds__(256)
void tcast(const float* __restrict__ in, short* __restrict__ out, int R, int C) {
  __shared__ float tl[32][33];
  const int t = threadIdx.x;
  const int r0 = blockIdx.y * 32, c0 = blockIdx.x * 32;
  const int tr = t >> 3, tc4 = (t & 7) * 4;
  float4 v = *(const float4*)&in[(size_t)(r0 + tr) * C + c0 + tc4];
  tl[tr][tc4] = v.x; tl[tr][tc4 + 1] = v.y; tl[tr][tc4 + 2] = v.z; tl[tr][tc4 + 3] = v.w;
  __syncthreads();
  short4 o = make_short4(f2bf(tl[tc4][tr]), f2bf(tl[tc4 + 1][tr]),
                         f2bf(tl[tc4 + 2][tr]), f2bf(tl[tc4 + 3][tr]));
  *(short4*)&out[(size_t)(c0 + tr) * R + r0 + tc4] = o;
}

// ---------------------------------------------------------------- GEMM (bf16 MFMA)
// C[M,N] = A[M,K](bf16) @ Wt[N,K]^T(bf16) + bias(f32). 256 thr = 4 waves (2x2),
// tile BM x 128, BK=32, wave = (BM/2) x 64 = MI x 4 frags of 16x16.
// EPI: 0 = f32 row-major, 1 = bf16 row-major, 2 = QKV split (Q,K head-major
// swizzled; V transposed swizzled) for the attention kernel.
template<int BM, int GELU, int EPI>
__global__ __launch_bounds__(256)
void gemm_bf16(const short* __restrict__ A, const short* __restrict__ Wt,
               const float* __restrict__ bias,
               float* __restrict__ Cf, short* __restrict__ Cb,
               short* __restrict__ qsw, short* __restrict__ ksw,
               short* __restrict__ vsw, int K, int N) {
  constexpr int MI = BM / 32;                 // frags per wave in M (4 or 2)
  __shared__ short As[BM * 32] __attribute__((aligned(16)));
  __shared__ short Bs[128 * 32] __attribute__((aligned(16)));
  const int t = threadIdx.x;
  const int w = t >> 6, l = t & 63, g = l >> 4, r = l & 15;
  const int wm = w >> 1, wn = w & 1;
  const int m0 = blockIdx.y * BM, n0 = blockIdx.x * 128;
  f32x4 acc[MI][4] = {};
  for (int k0 = 0; k0 < K; k0 += 32) {
    __syncthreads();                          // prior tile's reads done
#pragma unroll
    for (int iss = 0; iss < BM / 64; ++iss) { // A tile: [BM][32] shorts
      int q = iss * 256 + t;
      gload16(A + (size_t)(m0 + (q >> 2)) * K + k0 + (q & 3) * 8, (char*)As + q * 16);
    }
#pragma unroll
    for (int iss = 0; iss < 2; ++iss) {       // B tile: [128][32] shorts (from W^T)
      int q = iss * 256 + t;
      gload16(Wt + (size_t)(n0 + (q >> 2)) * K + k0 + (q & 3) * 8, (char*)Bs + q * 16);
    }
    __syncthreads();                          // stage visible (vmcnt drained)
    bf16x8 aF[MI], bF[4];
#pragma unroll
    for (int mi = 0; mi < MI; ++mi)
      aF[mi] = *(const bf16x8*)(As + (wm * (MI * 16) + mi * 16 + r) * 32 + g * 8);
#pragma unroll
    for (int ni = 0; ni < 4; ++ni)
      bF[ni] = *(const bf16x8*)(Bs + (wn * 64 + ni * 16 + r) * 32 + g * 8);
#pragma unroll
    for (int mi = 0; mi < MI; ++mi)
#pragma unroll
      for (int ni = 0; ni < 4; ++ni)
        acc[mi][ni] = __builtin_amdgcn_mfma_f32_16x16x32_bf16(aF[mi], bF[ni], acc[mi][ni], 0, 0, 0);
  }
  // epilogue: C/D layout col = lane&15, row = (lane>>4)*4 + reg  [m89/m91]
#pragma unroll
  for (int mi = 0; mi < MI; ++mi) {
#pragma unroll
    for (int ni = 0; ni < 4; ++ni) {
      const int n  = n0 + wn * 64 + ni * 16 + r;
      const int mB = m0 + wm * (MI * 16) + mi * 16 + g * 4;
      float vals[4];
#pragma unroll
      for (int j = 0; j < 4; ++j) {
        float v = acc[mi][ni][j] + bias[n];
        if (GELU) v = 0.5f * v * (1.0f + erff(v * 0.70710678118654752f));
        vals[j] = v;
      }
      if (EPI == 0) {
#pragma unroll
        for (int j = 0; j < 4; ++j) Cf[(size_t)(mB + j) * N + n] = vals[j];
      } else if (EPI == 1) {
#pragma unroll
        for (int j = 0; j < 4; ++j) Cb[(size_t)(mB + j) * N + n] = f2bf(vals[j]);
      } else {
        const int b = mB >> 11, s = mB & 2047;
        if (n < 512) {                        // Q: [b][h][s][d], d-swizzled by s&7
          const int hh = n >> 6, d = n & 63;
          const size_t rb = (size_t)(b * 8 + hh) * 2048;
#pragma unroll
          for (int j = 0; j < 4; ++j)
            qsw[(rb + s + j) * 64 + (d ^ (((s + j) & 7) << 3))] = f2bf(vals[j]);
        } else if (n < 1024) {                // K: same layout as Q
          const int hh = (n - 512) >> 6, d = (n - 512) & 63;
          const size_t rb = (size_t)(b * 8 + hh) * 2048;
#pragma unroll
          for (int j = 0; j < 4; ++j)
            ksw[(rb + s + j) * 64 + (d ^ (((s + j) & 7) << 3))] = f2bf(vals[j]);
        } else {                              // V: [b][h][d][s], s-swizzled by d&7
          const int hh = (n - 1024) >> 6, d = (n - 1024) & 63;
          short4 pk = make_short4(f2bf(vals[0]), f2bf(vals[1]), f2bf(vals[2]), f2bf(vals[3]));
          *(short4*)&vsw[(size_t)((b * 8 + hh) * 64 + d) * 2048 + (s ^ ((d & 7) << 3))] = pk;
        }
      }
    }
  }
}

// ---------------------------------------------------------------- Attention (bf16 MFMA)
// Block = 64 q-rows of one (b,h); 4 waves x 16 rows. KV tiles of 64.
// Q/K/V staged via linear global_load_lds from pre-swizzled global layouts;
// all fragment ds_read_b128 are conflict-free (XOR swizzle, <=2-way).
__global__ __launch_bounds__(256)
void attn_mfma(const short* __restrict__ qsw, const short* __restrict__ ksw,
               const short* __restrict__ vsw, short* __restrict__ attn_o) {
  __shared__ short Qs[64 * 64] __attribute__((aligned(16)));
  __shared__ short Ks[64 * 64] __attribute__((aligned(16)));
  __shared__ short Vs[64 * 64] __attribute__((aligned(16)));
  __shared__ short Ps[4 * 16 * 64] __attribute__((aligned(16)));
  const int t = threadIdx.x;
  const int w = t >> 6, l = t & 63, g = l >> 4, r = l & 15;
  const int bh = blockIdx.y;                  // b*8 + h
  const int q0 = blockIdx.x * 64;
  const short* qb = qsw + ((size_t)bh * 2048 + q0) * 64;
  const short* kb = ksw + (size_t)bh * 2048 * 64;
  const short* vb = vsw + (size_t)bh * 64 * 2048;

  // stage Q tile [64 rows][64 shorts, swizzled-in-row]
#pragma unroll
  for (int iss = 0; iss < 2; ++iss) {
    int q = iss * 256 + t;
    gload16(qb + (q >> 3) * 64 + (q & 7) * 8, (char*)Qs + q * 16);
  }
  __syncthreads();
  // hoist Q A-frags: row = w*16+r, k = kh*32 + g*8 + i
  const int qrow = w * 16 + r;
  bf16x8 qf[2];
#pragma unroll
  for (int kh = 0; kh < 2; ++kh)
    qf[kh] = *(const bf16x8*)(Qs + qrow * 64 + ((kh * 32 + g * 8) ^ ((qrow & 7) << 3)));

  f32x4 o[4] = {};
  float mL[4] = {-3e38f, -3e38f, -3e38f, -3e38f};
  float lsum[4] = {};
  short* Pw = Ps + w * 1024;                  // per-wave P tile [16][64]

  for (int kt = 0; kt < S; kt += 64) {
    __syncthreads();                          // prior tile's K/V reads done
#pragma unroll
    for (int iss = 0; iss < 2; ++iss) {       // K tile: rows = key
      int q = iss * 256 + t;
      gload16(kb + (kt + (q >> 3)) * 64 + (q & 7) * 8, (char*)Ks + q * 16);
    }
#pragma unroll
    for (int iss = 0; iss < 2; ++iss) {       // V tile: rows = d (transposed global)
      int q = iss * 256 + t;
      gload16(vb + (q >> 3) * 2048 + kt + (q & 7) * 8, (char*)Vs + q * 16);
    }
    __syncthreads();
    // S = Q K^T : 4 col-frags x 2 k-halves
    f32x4 sc[4] = {};
#pragma unroll
    for (int kh = 0; kh < 2; ++kh) {
      bf16x8 a = qf[kh];
#pragma unroll
      for (int cs = 0; cs < 4; ++cs) {
        const int kr = cs * 16 + r;           // key row in LDS
        bf16x8 bfr = *(const bf16x8*)(Ks + kr * 64 + ((kh * 32 + g * 8) ^ ((kr & 7) << 3)));
        sc[cs] = __builtin_amdgcn_mfma_f32_16x16x32_bf16(a, bfr, sc[cs], 0, 0, 0);
      }
    }
    // online softmax (log2 domain), rows g*4+j, reduce across 16 lanes
    float p[4][4], rs[4];
#pragma unroll
    for (int j = 0; j < 4; ++j) {
      float tj = fmaxf(fmaxf(sc[0][j], sc[1][j]), fmaxf(sc[2][j], sc[3][j])) * C_QK;
      tj = fmaxf(tj, __shfl_xor(tj, 1));
      tj = fmaxf(tj, __shfl_xor(tj, 2));
      tj = fmaxf(tj, __shfl_xor(tj, 4));
      tj = fmaxf(tj, __shfl_xor(tj, 8));
      float mn = fmaxf(mL[j], tj);
      rs[j] = exp2f(mL[j] - mn);
      mL[j] = mn;
      float rsum = 0.0f;
#pragma unroll
      for (int cs = 0; cs < 4; ++cs) {
        float pv = exp2f(sc[cs][j] * C_QK - mn);
        p[cs][j] = pv;
        rsum += pv;
      }
      rsum += __shfl_xor(rsum, 1);
      rsum += __shfl_xor(rsum, 2);
      rsum += __shfl_xor(rsum, 4);
      rsum += __shfl_xor(rsum, 8);
      lsum[j] = lsum[j] * rs[j] + rsum;
    }
    // rescale O, write P (bf16, swizzled) to wave-private LDS
#pragma unroll
    for (int cs = 0; cs < 4; ++cs)
#pragma unroll
      for (int j = 0; j < 4; ++j) {
        o[cs][j] *= rs[j];
        const int pr = g * 4 + j, pc = cs * 16 + r;
        Pw[pr * 64 + (pc ^ ((pr & 7) << 3))] = f2bf(p[cs][j]);
      }
    // O += P V : A = P rows (= q local), B = V (rows = d in LDS)
#pragma unroll
    for (int kh = 0; kh < 2; ++kh) {
      bf16x8 pa = *(const bf16x8*)(Pw + r * 64 + ((kh * 32 + g * 8) ^ ((r & 7) << 3)));
#pragma unroll
      for (int cs = 0; cs < 4; ++cs) {
        const int dr = cs * 16 + r;           // d row in LDS
        bf16x8 vf = *(const bf16x8*)(Vs + dr * 64 + ((kh * 32 + g * 8) ^ ((dr & 7) << 3)));
        o[cs] = __builtin_amdgcn_mfma_f32_16x16x32_bf16(pa, vf, o[cs], 0, 0, 0);
      }
    }
  }
  // finalize: out[b, s, h*64 + d] bf16 row-major [M][512]
  const int b = bh >> 3, hh = bh & 7;
  float inv[4];
#pragma unroll
  for (int j = 0; j < 4; ++j) inv[j] = 1.0f / lsum[j];
#pragma unroll
  for (int cs = 0; cs < 4; ++cs)
#pragma unroll
    for (int j = 0; j < 4; ++j) {
      const int row = q0 + w * 16 + g * 4 + j;
      const int col = hh * 64 + cs * 16 + r;
      attn_o[(size_t)(b * 2048 + row) * 512 + col] = f2bf(o[cs][j] * inv[j]);
    }
}

// ---------------------------------------------------------------- Add + LayerNorm (fp32)
// out = LN(a + res)*g + be ; optional bf16 copy of the output (for next GEMM's A).
template<int WB>
__global__ __launch_bounds__(256)
void add_ln(const float* __restrict__ a, const float* __restrict__ res,
            const float* __restrict__ g_, const float* __restrict__ be,
            float* __restrict__ out, short* __restrict__ outb) {
  const int row = blockIdx.x;
  const int t = threadIdx.x;
  const size_t off = (size_t)row * D;
  float x0 = a[off + t] + res[off + t];
  float x1 = a[off + t + 256] + res[off + t + 256];
  float sum = x0 + x1;
  float sq  = x0 * x0 + x1 * x1;
#pragma unroll
  for (int o2 = 32; o2 > 0; o2 >>= 1) {
    sum += __shfl_down(sum, o2);
    sq  += __shfl_down(sq, o2);
  }
  __shared__ float ssum[4], ssq[4];
  const int wid = t >> 6;
  if ((t & 63) == 0) { ssum[wid] = sum; ssq[wid] = sq; }
  __syncthreads();
  if (t == 0) {
    ssum[0] = ssum[0] + ssum[1] + ssum[2] + ssum[3];
    ssq[0]  = ssq[0] + ssq[1] + ssq[2] + ssq[3];
  }
  __syncthreads();
  float mu   = ssum[0] * (1.0f / D);
  float var  = ssq[0] * (1.0f / D) - mu * mu;
  float rstd = rsqrtf(var + 1e-5f);
  float y0 = (x0 - mu) * rstd * g_[t] + be[t];
  float y1 = (x1 - mu) * rstd * g_[t + 256] + be[t + 256];
  out[off + t] = y0;
  out[off + t + 256] = y1;
  if (WB) {
    outb[off + t] = f2bf(y0);
    outb[off + t + 256] = f2bf(y1);
  }
}

// ---------------------------------------------------------------- launch
extern "C" void kernel_launch(void* const* d_in, const int* in_sizes, int n_in,
                              void* d_out, int out_size, void* d_ws, size_t ws_size,
                              hipStream_t stream) {
  const float* x     = (const float*)d_in[0];
  const float* w_qkv = (const float*)d_in[1];
  const float* b_qkv = (const float*)d_in[2];
  const float* w_o   = (const float*)d_in[3];
  const float* b_o   = (const float*)d_in[4];
  const float* w1    = (const float*)d_in[5];
  const float* b1    = (const float*)d_in[6];
  const float* w2    = (const float*)d_in[7];
  const float* b2    = (const float*)d_in[8];
  const float* g1    = (const float*)d_in[9];
  const float* be1   = (const float*)d_in[10];
  const float* g2    = (const float*)d_in[11];
  const float* be2   = (const float*)d_in[12];
  float* out = (float*)d_out;
  (void)in_sizes; (void)n_in; (void)out_size; (void)ws_size;

  // Workspace layout (~83 MB):
  const size_t MD = (size_t)M * 512;
  short* q_sw = (short*)d_ws;           // [B][H][S][64] swz     8.4 MB
  short* k_sw = q_sw + MD;              // [B][H][S][64] swz     8.4 MB
  short* v_sw = k_sw + MD;              // [B][H][64][S] swz     8.4 MB
  short* a_o  = v_sw + MD;              // attn out [M][512]     8.4 MB
  short* h    = q_sw;                   // FFN hidden [M][2048] overlays q/k/v/a_o (dead)
  short* xb   = a_o + MD;               // x bf16 [M][512]       8.4 MB
  short* ln1b = xb;                     // ln1 bf16 overlays xb (dead after GEMM1)
  short* wtq  = xb + MD;                // W^T bf16 weights      6.3 MB
  short* wto  = wtq + (size_t)1536 * 512;
  short* wt1  = wto + (size_t)512 * 512;
  short* wt2  = wt1 + (size_t)512 * 2048;
  float* buf  = (float*)(wt2 + (size_t)2048 * 512);  // f32 [M][512]  16.8 MB
  float* ln1  = buf + MD;                            // f32 [M][512]  16.8 MB

  // prep: casts + weight transposes
  cast_x<<<4096, 256, 0, stream>>>((const float4*)x, (short4*)xb);
  tcast<<<dim3(48, 16), 256, 0, stream>>>(w_qkv, wtq, 512, 1536);
  tcast<<<dim3(16, 16), 256, 0, stream>>>(w_o,  wto, 512, 512);
  tcast<<<dim3(64, 16), 256, 0, stream>>>(w1,   wt1, 512, 2048);
  tcast<<<dim3(16, 64), 256, 0, stream>>>(w2,   wt2, 2048, 512);

  // QKV projection -> swizzled Q/K/V layouts
  gemm_bf16<128, 0, 2><<<dim3(12, 64), 256, 0, stream>>>(
      xb, wtq, b_qkv, nullptr, nullptr, q_sw, k_sw, v_sw, 512, 1536);
  // attention
  attn_mfma<<<dim3(32, 32), 256, 0, stream>>>(q_sw, k_sw, v_sw, a_o);
  // O projection (f32 out for LN)
  gemm_bf16<64, 0, 0><<<dim3(4, 128), 256, 0, stream>>>(
      a_o, wto, b_o, buf, nullptr, nullptr, nullptr, nullptr, 512, 512);
  // LN1 (+ residual x), dual f32/bf16 out
  add_ln<1><<<M, 256, 0, stream>>>(buf, x, g1, be1, ln1, ln1b);
  // FFN1 + exact GELU (bf16 out)
  gemm_bf16<128, 1, 1><<<dim3(16, 64), 256, 0, stream>>>(
      ln1b, wt1, b1, nullptr, h, nullptr, nullptr, nullptr, 512, 2048);
  // FFN2 (f32 out)
  gemm_bf16<64, 0, 0><<<dim3(4, 128), 256, 0, stream>>>(
      h, wt2, b2, buf, nullptr, nullptr, nullptr, nullptr, 2048, 512);
  // LN2 (+ residual ln1) -> final output
  add_ln<0><<<M, 256, 0, stream>>>(buf, ln1, g2, be2, out, nullptr);
}

// Round 3
// 305.736 us; speedup vs baseline: 7.8094x; 1.1906x over previous
//
#include <hip/hip_runtime.h>
#include <math.h>

// Problem constants (B,S,D,H,F = 4,2048,512,8,2048)
constexpr int B = 4, S = 2048, D = 512, H = 8, HD = 64, F = 2048;
constexpr int M = B * S;                      // 8192 token rows
constexpr float C_QK = 0.125f * 1.44269504088896340736f;  // SCALE * log2(e)

typedef __bf16 bf16x8 __attribute__((ext_vector_type(8)));
typedef float  f32x4  __attribute__((ext_vector_type(4)));
typedef float  f32x16 __attribute__((ext_vector_type(16)));

static __device__ __forceinline__ short f2bf(float f) {
  return __builtin_bit_cast(short, (__bf16)f);   // RNE via fptrunc
}

static __device__ __forceinline__ void gload16(const void* g, void* l) {
  __builtin_amdgcn_global_load_lds(
      (const __attribute__((address_space(1))) unsigned int*)g,
      (__attribute__((address_space(3))) unsigned int*)l, 16, 0, 0);
}

// ---------------------------------------------------------------- prep
__global__ __launch_bounds__(256)
void cast_x(const float4* __restrict__ in, short4* __restrict__ out) {
  int i = blockIdx.x * 256 + threadIdx.x;
  float4 v = in[i];
  out[i] = make_short4(f2bf(v.x), f2bf(v.y), f2bf(v.z), f2bf(v.w));
}

// fp32 [R][C] -> bf16 [C][R] transpose-cast (weights -> W^T for GEMM B-op).
__global__ __launch_bounds__(256)
void tcast(const float* __restrict__ in, short* __restrict__ out, int R, int C) {
  __shared__ float tl[32][33];
  const int t = threadIdx.x;
  const int r0 = blockIdx.y * 32, c0 = blockIdx.x * 32;
  const int tr = t >> 3, tc4 = (t & 7) * 4;
  float4 v = *(const float4*)&in[(size_t)(r0 + tr) * C + c0 + tc4];
  tl[tr][tc4] = v.x; tl[tr][tc4 + 1] = v.y; tl[tr][tc4 + 2] = v.z; tl[tr][tc4 + 3] = v.w;
  __syncthreads();
  short4 o = make_short4(f2bf(tl[tc4][tr]), f2bf(tl[tc4 + 1][tr]),
                         f2bf(tl[tc4 + 2][tr]), f2bf(tl[tc4 + 3][tr]));
  *(short4*)&out[(size_t)(c0 + tr) * R + r0 + tc4] = o;
}

// ---------------------------------------------------------------- GEMM (bf16 MFMA)
// C[M,N] = A[M,K](bf16) @ Wt[N,K]^T(bf16) + bias(f32). 4 waves (2x2),
// tile BM x 128, BK=32. EPI: 0 = f32 row-major, 1 = bf16 row-major,
// 2 = QKV split (Q scaled by C_QK, Q/K head-major swizzled; V transposed swz).
template<int BM, int GELU, int EPI>
__global__ __launch_bounds__(256)
void gemm_bf16(const short* __restrict__ A, const short* __restrict__ Wt,
               const float* __restrict__ bias,
               float* __restrict__ Cf, short* __restrict__ Cb,
               short* __restrict__ qsw, short* __restrict__ ksw,
               short* __restrict__ vsw, int K, int N) {
  constexpr int MI = BM / 32;
  __shared__ short As[BM * 32] __attribute__((aligned(16)));
  __shared__ short Bs[128 * 32] __attribute__((aligned(16)));
  const int t = threadIdx.x;
  const int w = t >> 6, l = t & 63, g = l >> 4, r = l & 15;
  const int wm = w >> 1, wn = w & 1;
  const int m0 = blockIdx.y * BM, n0 = blockIdx.x * 128;
  f32x4 acc[MI][4] = {};
  for (int k0 = 0; k0 < K; k0 += 32) {
    __syncthreads();
#pragma unroll
    for (int iss = 0; iss < BM / 64; ++iss) {
      int q = iss * 256 + t;
      gload16(A + (size_t)(m0 + (q >> 2)) * K + k0 + (q & 3) * 8, (char*)As + q * 16);
    }
#pragma unroll
    for (int iss = 0; iss < 2; ++iss) {
      int q = iss * 256 + t;
      gload16(Wt + (size_t)(n0 + (q >> 2)) * K + k0 + (q & 3) * 8, (char*)Bs + q * 16);
    }
    __syncthreads();
    bf16x8 aF[MI], bF[4];
#pragma unroll
    for (int mi = 0; mi < MI; ++mi)
      aF[mi] = *(const bf16x8*)(As + (wm * (MI * 16) + mi * 16 + r) * 32 + g * 8);
#pragma unroll
    for (int ni = 0; ni < 4; ++ni)
      bF[ni] = *(const bf16x8*)(Bs + (wn * 64 + ni * 16 + r) * 32 + g * 8);
#pragma unroll
    for (int mi = 0; mi < MI; ++mi)
#pragma unroll
      for (int ni = 0; ni < 4; ++ni)
        acc[mi][ni] = __builtin_amdgcn_mfma_f32_16x16x32_bf16(aF[mi], bF[ni], acc[mi][ni], 0, 0, 0);
  }
  // epilogue: C/D col = lane&15, row = (lane>>4)*4 + reg  [m89/m91]
#pragma unroll
  for (int mi = 0; mi < MI; ++mi) {
#pragma unroll
    for (int ni = 0; ni < 4; ++ni) {
      const int n  = n0 + wn * 64 + ni * 16 + r;
      const int mB = m0 + wm * (MI * 16) + mi * 16 + g * 4;
      float vals[4];
#pragma unroll
      for (int j = 0; j < 4; ++j) {
        float v = acc[mi][ni][j] + bias[n];
        if (GELU) v = 0.5f * v * (1.0f + erff(v * 0.70710678118654752f));
        vals[j] = v;
      }
      if (EPI == 0) {
#pragma unroll
        for (int j = 0; j < 4; ++j) Cf[(size_t)(mB + j) * N + n] = vals[j];
      } else if (EPI == 1) {
#pragma unroll
        for (int j = 0; j < 4; ++j) Cb[(size_t)(mB + j) * N + n] = f2bf(vals[j]);
      } else {
        const int b = mB >> 11, s = mB & 2047;
        if (n < 512) {                        // Q (scaled): [b][h][s][d^swz]
          const int hh = n >> 6, d = n & 63;
          const size_t rb = (size_t)(b * 8 + hh) * 2048;
#pragma unroll
          for (int j = 0; j < 4; ++j)
            qsw[(rb + s + j) * 64 + (d ^ (((s + j) & 7) << 3))] = f2bf(vals[j] * C_QK);
        } else if (n < 1024) {                // K: same layout, unscaled
          const int hh = (n - 512) >> 6, d = (n - 512) & 63;
          const size_t rb = (size_t)(b * 8 + hh) * 2048;
#pragma unroll
          for (int j = 0; j < 4; ++j)
            ksw[(rb + s + j) * 64 + (d ^ (((s + j) & 7) << 3))] = f2bf(vals[j]);
        } else {                              // V: [b][h][d][s^swz]
          const int hh = (n - 1024) >> 6, d = (n - 1024) & 63;
          short4 pk = make_short4(f2bf(vals[0]), f2bf(vals[1]), f2bf(vals[2]), f2bf(vals[3]));
          *(short4*)&vsw[(size_t)((b * 8 + hh) * 64 + d) * 2048 + (s ^ ((d & 7) << 3))] = pk;
        }
      }
    }
  }
}

// ---------------------------------------------------------------- Attention v2
// m214-style: 4 waves x 32 q-rows (block = 128 q), KV tiles of 64, 32x32x16 MFMA,
// swapped QK^T (S^T: col=q lane-local), in-register softmax + defer-max,
// cvt_pk+permlane32_swap builds PV A-frags in registers (no P LDS round-trip).
__global__ __launch_bounds__(256)
void attn_mfma(const short* __restrict__ qsw, const short* __restrict__ ksw,
               const short* __restrict__ vsw, short* __restrict__ attn_o) {
  __shared__ short Qs[128 * 64] __attribute__((aligned(16)));
  __shared__ short Ks[64 * 64] __attribute__((aligned(16)));
  __shared__ short Vs[64 * 64] __attribute__((aligned(16)));
  const int t = threadIdx.x;
  const int w = t >> 6, l = t & 63;
  const int c = l & 31, hi = l >> 5;          // c = q (QK out) / d (PV out) col
  const int bh = blockIdx.y;
  const int q0 = blockIdx.x * 128;
  const short* qb = qsw + ((size_t)bh * 2048 + q0) * 64;
  const short* kb = ksw + (size_t)bh * 2048 * 64;
  const short* vb = vsw + (size_t)bh * 64 * 2048;

  // stage Q tile [128][64] (swizzle already baked into global data)
#pragma unroll
  for (int iss = 0; iss < 4; ++iss) {
    int q = iss * 256 + t;
    gload16(qb + (q >> 3) * 64 + (q & 7) * 8, (char*)Qs + q * 16);
  }
  __syncthreads();
  // hoist Q B-frags: col = q = w*32 + c, k-chunk = dc*16 + hi*8
  const int qrow = w * 32 + c;
  const int swz = (c & 7) << 3;               // row&7 == c&7 for all our rows
  bf16x8 qf[4];
#pragma unroll
  for (int dc = 0; dc < 4; ++dc)
    qf[dc] = *(const bf16x8*)(Qs + qrow * 64 + ((dc * 16 + hi * 8) ^ swz));

  f32x16 o0 = {}, o1 = {};                    // O^(d-blocks): col=d, rows=q
  float m_run = -3e38f, l_run = 0.0f;         // per lane: stats for q = w*32+c

  for (int kt = 0; kt < S; kt += 64) {
    __syncthreads();
#pragma unroll
    for (int iss = 0; iss < 2; ++iss) {       // K tile [64 keys][64 d]
      int q = iss * 256 + t;
      gload16(kb + (size_t)(kt + (q >> 3)) * 64 + (q & 7) * 8, (char*)Ks + q * 16);
    }
#pragma unroll
    for (int iss = 0; iss < 2; ++iss) {       // V tile [64 d][64 s]
      int q = iss * 256 + t;
      gload16(vb + (size_t)(q >> 3) * 2048 + kt + (q & 7) * 8, (char*)Vs + q * 16);
    }
    __syncthreads();

    // S^T = K Q^T (scale pre-folded into Q): s0 keys 0..31, s1 keys 32..63
    f32x16 s0 = {}, s1 = {};
#pragma unroll
    for (int dc = 0; dc < 4; ++dc) {
      const int koff = (dc * 16 + hi * 8) ^ swz;
      bf16x8 kf0 = *(const bf16x8*)(Ks + c * 64 + koff);
      bf16x8 kf1 = *(const bf16x8*)(Ks + (32 + c) * 64 + koff);
      s0 = __builtin_amdgcn_mfma_f32_32x32x16_bf16(kf0, qf[dc], s0, 0, 0, 0);
      s1 = __builtin_amdgcn_mfma_f32_32x32x16_bf16(kf1, qf[dc], s1, 0, 0, 0);
    }
    // in-lane softmax for q = w*32+c (32 values; key = 32kb + (j&3)+8(j>>2)+4hi)
    float tmax = -3e38f;
#pragma unroll
    for (int j = 0; j < 16; ++j) tmax = fmaxf(tmax, fmaxf(s0[j], s1[j]));
    tmax = fmaxf(tmax, __shfl_xor(tmax, 32, 64));
    if (__any(tmax - m_run > 8.0f)) {         // T13 defer-max (log2 domain)
      float mnew = fmaxf(m_run, tmax);
      float rs = __builtin_amdgcn_exp2f(m_run - mnew);
      m_run = mnew;
      l_run *= rs;
#pragma unroll
      for (int j = 0; j < 16; ++j) {          // per-row rescale: q_rel(j,hi)
        float rj = __shfl(rs, (j & 3) + 8 * (j >> 2) + 4 * hi, 64);
        o0[j] *= rj; o1[j] *= rj;
      }
    }
    float rsum = 0.0f;
#pragma unroll
    for (int j = 0; j < 16; ++j) {
      s0[j] = __builtin_amdgcn_exp2f(s0[j] - m_run);
      s1[j] = __builtin_amdgcn_exp2f(s1[j] - m_run);
      rsum += s0[j] + s1[j];
    }
    rsum += __shfl_xor(rsum, 32, 64);
    l_run += rsum;

    // build PV A-frags (T12) and accumulate O
#pragma unroll
    for (int kc = 0; kc < 4; ++kc) {
      const int jb = (kc & 1) * 8;
      int u0, u1, v0, v1;
      if (kc < 2) {
        asm("v_cvt_pk_bf16_f32 %0, %1, %2" : "=v"(u0) : "v"(s0[jb + 0]), "v"(s0[jb + 1]));
        asm("v_cvt_pk_bf16_f32 %0, %1, %2" : "=v"(u1) : "v"(s0[jb + 2]), "v"(s0[jb + 3]));
        asm("v_cvt_pk_bf16_f32 %0, %1, %2" : "=v"(v0) : "v"(s0[jb + 4]), "v"(s0[jb + 5]));
        asm("v_cvt_pk_bf16_f32 %0, %1, %2" : "=v"(v1) : "v"(s0[jb + 6]), "v"(s0[jb + 7]));
      } else {
        asm("v_cvt_pk_bf16_f32 %0, %1, %2" : "=v"(u0) : "v"(s1[jb + 0]), "v"(s1[jb + 1]));
        asm("v_cvt_pk_bf16_f32 %0, %1, %2" : "=v"(u1) : "v"(s1[jb + 2]), "v"(s1[jb + 3]));
        asm("v_cvt_pk_bf16_f32 %0, %1, %2" : "=v"(v0) : "v"(s1[jb + 4]), "v"(s1[jb + 5]));
        asm("v_cvt_pk_bf16_f32 %0, %1, %2" : "=v"(v1) : "v"(s1[jb + 6]), "v"(s1[jb + 7]));
      }
      asm volatile("v_permlane32_swap_b32 %0, %1" : "+v"(u0), "+v"(v0));
      asm volatile("v_permlane32_swap_b32 %0, %1" : "+v"(u1), "+v"(v1));
      int pw[4] = {u0, u1, v0, v1};
      bf16x8 pa = __builtin_bit_cast(bf16x8, *(int4*)pw);
      const int voff = (kc * 16 + hi * 8) ^ swz;
      bf16x8 vf0 = *(const bf16x8*)(Vs + c * 64 + voff);
      bf16x8 vf1 = *(const bf16x8*)(Vs + (32 + c) * 64 + voff);
      o0 = __builtin_amdgcn_mfma_f32_32x32x16_bf16(pa, vf0, o0, 0, 0, 0);
      o1 = __builtin_amdgcn_mfma_f32_32x32x16_bf16(pa, vf1, o1, 0, 0, 0);
    }
  }
  // finalize: O col = d = 32*db + c, rows q_rel = (j&3)+8(j>>2)+4hi
  const int b = bh >> 3, hh = bh & 7;
  float inv = 1.0f / l_run;
#pragma unroll
  for (int j = 0; j < 16; ++j) {
    const int q_rel = (j & 3) + 8 * (j >> 2) + 4 * hi;
    float invq = __shfl(inv, q_rel, 64);
    const size_t row = (size_t)(b * 2048 + q0 + w * 32 + q_rel) * 512 + hh * 64;
    attn_o[row + c]      = f2bf(o0[j] * invq);
    attn_o[row + 32 + c] = f2bf(o1[j] * invq);
  }
}

// ---------------------------------------------------------------- Add + LayerNorm (fp32)
template<int WB>
__global__ __launch_bounds__(256)
void add_ln(const float* __restrict__ a, const float* __restrict__ res,
            const float* __restrict__ g_, const float* __restrict__ be,
            float* __restrict__ out, short* __restrict__ outb) {
  const int row = blockIdx.x;
  const int t = threadIdx.x;
  const size_t off = (size_t)row * D;
  float x0 = a[off + t] + res[off + t];
  float x1 = a[off + t + 256] + res[off + t + 256];
  float sum = x0 + x1;
  float sq  = x0 * x0 + x1 * x1;
#pragma unroll
  for (int o2 = 32; o2 > 0; o2 >>= 1) {
    sum += __shfl_down(sum, o2);
    sq  += __shfl_down(sq, o2);
  }
  __shared__ float ssum[4], ssq[4];
  const int wid = t >> 6;
  if ((t & 63) == 0) { ssum[wid] = sum; ssq[wid] = sq; }
  __syncthreads();
  if (t == 0) {
    ssum[0] = ssum[0] + ssum[1] + ssum[2] + ssum[3];
    ssq[0]  = ssq[0] + ssq[1] + ssq[2] + ssq[3];
  }
  __syncthreads();
  float mu   = ssum[0] * (1.0f / D);
  float var  = ssq[0] * (1.0f / D) - mu * mu;
  float rstd = rsqrtf(var + 1e-5f);
  float y0 = (x0 - mu) * rstd * g_[t] + be[t];
  float y1 = (x1 - mu) * rstd * g_[t + 256] + be[t + 256];
  out[off + t] = y0;
  out[off + t + 256] = y1;
  if (WB) {
    outb[off + t] = f2bf(y0);
    outb[off + t + 256] = f2bf(y1);
  }
}

// ---------------------------------------------------------------- launch
extern "C" void kernel_launch(void* const* d_in, const int* in_sizes, int n_in,
                              void* d_out, int out_size, void* d_ws, size_t ws_size,
                              hipStream_t stream) {
  const float* x     = (const float*)d_in[0];
  const float* w_qkv = (const float*)d_in[1];
  const float* b_qkv = (const float*)d_in[2];
  const float* w_o   = (const float*)d_in[3];
  const float* b_o   = (const float*)d_in[4];
  const float* w1    = (const float*)d_in[5];
  const float* b1    = (const float*)d_in[6];
  const float* w2    = (const float*)d_in[7];
  const float* b2    = (const float*)d_in[8];
  const float* g1    = (const float*)d_in[9];
  const float* be1   = (const float*)d_in[10];
  const float* g2    = (const float*)d_in[11];
  const float* be2   = (const float*)d_in[12];
  float* out = (float*)d_out;
  (void)in_sizes; (void)n_in; (void)out_size; (void)ws_size;

  const size_t MD = (size_t)M * 512;
  short* q_sw = (short*)d_ws;           // [B][H][S][64] swz (pre-scaled)
  short* k_sw = q_sw + MD;
  short* v_sw = k_sw + MD;              // [B][H][64][S] swz
  short* a_o  = v_sw + MD;              // attn out [M][512]
  short* h    = q_sw;                   // FFN hidden overlays q/k/v/a_o (dead)
  short* xb   = a_o + MD;
  short* ln1b = xb;                     // ln1 bf16 overlays xb (dead after GEMM1)
  short* wtq  = xb + MD;
  short* wto  = wtq + (size_t)1536 * 512;
  short* wt1  = wto + (size_t)512 * 512;
  short* wt2  = wt1 + (size_t)512 * 2048;
  float* buf  = (float*)(wt2 + (size_t)2048 * 512);
  float* ln1  = buf + MD;

  cast_x<<<4096, 256, 0, stream>>>((const float4*)x, (short4*)xb);
  tcast<<<dim3(48, 16), 256, 0, stream>>>(w_qkv, wtq, 512, 1536);
  tcast<<<dim3(16, 16), 256, 0, stream>>>(w_o,  wto, 512, 512);
  tcast<<<dim3(64, 16), 256, 0, stream>>>(w1,   wt1, 512, 2048);
  tcast<<<dim3(16, 64), 256, 0, stream>>>(w2,   wt2, 2048, 512);

  gemm_bf16<128, 0, 2><<<dim3(12, 64), 256, 0, stream>>>(
      xb, wtq, b_qkv, nullptr, nullptr, q_sw, k_sw, v_sw, 512, 1536);
  attn_mfma<<<dim3(16, 32), 256, 0, stream>>>(q_sw, k_sw, v_sw, a_o);
  gemm_bf16<128, 0, 0><<<dim3(4, 64), 256, 0, stream>>>(
      a_o, wto, b_o, buf, nullptr, nullptr, nullptr, nullptr, 512, 512);
  add_ln<1><<<M, 256, 0, stream>>>(buf, x, g1, be1, ln1, ln1b);
  gemm_bf16<128, 1, 1><<<dim3(16, 64), 256, 0, stream>>>(
      ln1b, wt1, b1, nullptr, h, nullptr, nullptr, nullptr, 512, 2048);
  gemm_bf16<128, 0, 0><<<dim3(4, 64), 256, 0, stream>>>(
      h, wt2, b2, buf, nullptr, nullptr, nullptr, nullptr, 2048, 512);
  add_ln<0><<<M, 256, 0, stream>>>(buf, ln1, g2, be2, out, nullptr);
}

// Round 4
// 294.812 us; speedup vs baseline: 8.0988x; 1.0371x over previous
//
#include <hip/hip_runtime.h>
#include <math.h>

// Problem constants (B,S,D,H,F = 4,2048,512,8,2048)
constexpr int B = 4, S = 2048, D = 512, H = 8, HD = 64, F = 2048;
constexpr int M = B * S;                      // 8192 token rows
constexpr float C_QK = 0.125f * 1.44269504088896340736f;  // SCALE * log2(e)

typedef __bf16 bf16x8 __attribute__((ext_vector_type(8)));
typedef float  f32x4  __attribute__((ext_vector_type(4)));
typedef float  f32x16 __attribute__((ext_vector_type(16)));

static __device__ __forceinline__ short f2bf(float f) {
  return __builtin_bit_cast(short, (__bf16)f);   // RNE via fptrunc
}

static __device__ __forceinline__ void gload16(const void* g, void* l) {
  __builtin_amdgcn_global_load_lds(
      (const __attribute__((address_space(1))) unsigned int*)g,
      (__attribute__((address_space(3))) unsigned int*)l, 16, 0, 0);
}

// ---------------------------------------------------------------- prep (fused)
// [0,4096): x f32->bf16 cast. Rest: weight transpose-casts W[R][C] -> W^T bf16.
__global__ __launch_bounds__(256)
void prep_all(const float* __restrict__ x, short* __restrict__ xb,
              const float* __restrict__ w_qkv, short* __restrict__ wtq,
              const float* __restrict__ w_o,  short* __restrict__ wto,
              const float* __restrict__ w1,   short* __restrict__ wt1,
              const float* __restrict__ w2,   short* __restrict__ wt2) {
  __shared__ float tl[32][33];
  const int id = blockIdx.x;
  const int t = threadIdx.x;
  if (id < 4096) {
    int i = id * 256 + t;
    float4 v = ((const float4*)x)[i];
    ((short4*)xb)[i] = make_short4(f2bf(v.x), f2bf(v.y), f2bf(v.z), f2bf(v.w));
    return;
  }
  const float* in; short* out; int R, C, bx, by;
  if (id < 4864)      { int k = id - 4096; in = w_qkv; out = wtq; R = 512;  C = 1536; bx = k % 48; by = k / 48; }
  else if (id < 5120) { int k = id - 4864; in = w_o;   out = wto; R = 512;  C = 512;  bx = k % 16; by = k / 16; }
  else if (id < 6144) { int k = id - 5120; in = w1;    out = wt1; R = 512;  C = 2048; bx = k % 64; by = k / 64; }
  else                { int k = id - 6144; in = w2;    out = wt2; R = 2048; C = 512;  bx = k % 16; by = k / 16; }
  const int r0 = by * 32, c0 = bx * 32;
  const int tr = t >> 3, tc4 = (t & 7) * 4;
  float4 v = *(const float4*)&in[(size_t)(r0 + tr) * C + c0 + tc4];
  tl[tr][tc4] = v.x; tl[tr][tc4 + 1] = v.y; tl[tr][tc4 + 2] = v.z; tl[tr][tc4 + 3] = v.w;
  __syncthreads();
  short4 o = make_short4(f2bf(tl[tc4][tr]), f2bf(tl[tc4 + 1][tr]),
                         f2bf(tl[tc4 + 2][tr]), f2bf(tl[tc4 + 3][tr]));
  *(short4*)&out[(size_t)(c0 + tr) * R + r0 + tc4] = o;
}

// ---------------------------------------------------------------- GEMM (bf16 MFMA, 2-phase)
// C[M,N] = A[M,K] @ Wt[N,K]^T + bias. 128x128 tile, BK=64, double-buffered LDS,
// prefetch-next-then-compute, one barrier/step. XOR-swizzled stage/read pair:
// LDS[row][slot] = G[row][slot ^ (row&7)]  (slot = 16B chunk, 8 per 128B row).
// EPI: 0 = f32 row-major, 1 = bf16 row-major, 2 = QKV split for attention.
template<int GELU, int EPI>
__global__ __launch_bounds__(256)
void gemm_bf16(const short* __restrict__ A, const short* __restrict__ Wt,
               const float* __restrict__ bias,
               float* __restrict__ Cf, short* __restrict__ Cb,
               short* __restrict__ qsw, short* __restrict__ ksw,
               short* __restrict__ vsw, int K, int N) {
  __shared__ short As[2][128 * 64] __attribute__((aligned(16)));
  __shared__ short Bs[2][128 * 64] __attribute__((aligned(16)));
  const int t = threadIdx.x;
  const int w = t >> 6, l = t & 63, g = l >> 4, r = l & 15;
  const int wm = w >> 1, wn = w & 1;
  const int m0 = blockIdx.y * 128, n0 = blockIdx.x * 128;

  // stage: 4 issue-rounds each for A and B; row = q>>3, src chunk = (q&7)^(row&7)
#define STAGE_TILE(buf, k0)                                                     \
  {                                                                             \
    _Pragma("unroll")                                                           \
    for (int iss = 0; iss < 4; ++iss) {                                         \
      int q = iss * 256 + t;                                                    \
      int row = q >> 3, sl = (q & 7) ^ (row & 7);                               \
      gload16(A + (size_t)(m0 + row) * K + (k0) + sl * 8,                       \
              (char*)As[buf] + q * 16);                                         \
    }                                                                           \
    _Pragma("unroll")                                                           \
    for (int iss = 0; iss < 4; ++iss) {                                         \
      int q = iss * 256 + t;                                                    \
      int row = q >> 3, sl = (q & 7) ^ (row & 7);                               \
      gload16(Wt + (size_t)(n0 + row) * K + (k0) + sl * 8,                      \
              (char*)Bs[buf] + q * 16);                                         \
    }                                                                           \
  }

  f32x4 acc[4][4] = {};
  const int NS = K >> 6;
  STAGE_TILE(0, 0);
  __syncthreads();
  for (int st = 0; st < NS; ++st) {
    const int cur = st & 1;
    if (st + 1 < NS) STAGE_TILE(cur ^ 1, (st + 1) << 6);
    const short* Ac = As[cur];
    const short* Bc = Bs[cur];
#pragma unroll
    for (int kh = 0; kh < 2; ++kh) {
      const int cc = kh * 4 + g;              // 16B chunk index within row
      bf16x8 aF[4], bF[4];
#pragma unroll
      for (int mi = 0; mi < 4; ++mi) {
        const int row = wm * 64 + mi * 16 + r;
        aF[mi] = *(const bf16x8*)(Ac + row * 64 + ((cc ^ (r & 7)) << 3));
      }
#pragma unroll
      for (int ni = 0; ni < 4; ++ni) {
        const int row = wn * 64 + ni * 16 + r;
        bF[ni] = *(const bf16x8*)(Bc + row * 64 + ((cc ^ (r & 7)) << 3));
      }
#pragma unroll
      for (int mi = 0; mi < 4; ++mi)
#pragma unroll
        for (int ni = 0; ni < 4; ++ni)
          acc[mi][ni] = __builtin_amdgcn_mfma_f32_16x16x32_bf16(aF[mi], bF[ni], acc[mi][ni], 0, 0, 0);
    }
    __syncthreads();                          // drains next-tile vmcnt after compute
  }
#undef STAGE_TILE

  // epilogue: C/D col = lane&15, row = (lane>>4)*4 + reg  [m89/m91]
#pragma unroll
  for (int mi = 0; mi < 4; ++mi) {
#pragma unroll
    for (int ni = 0; ni < 4; ++ni) {
      const int n  = n0 + wn * 64 + ni * 16 + r;
      const int mB = m0 + wm * 64 + mi * 16 + g * 4;
      float vals[4];
#pragma unroll
      for (int j = 0; j < 4; ++j) {
        float v = acc[mi][ni][j] + bias[n];
        if (GELU) v = 0.5f * v * (1.0f + erff(v * 0.70710678118654752f));
        vals[j] = v;
      }
      if (EPI == 0) {
#pragma unroll
        for (int j = 0; j < 4; ++j) Cf[(size_t)(mB + j) * N + n] = vals[j];
      } else if (EPI == 1) {
#pragma unroll
        for (int j = 0; j < 4; ++j) Cb[(size_t)(mB + j) * N + n] = f2bf(vals[j]);
      } else {
        const int b = mB >> 11, s = mB & 2047;
        if (n < 512) {                        // Q (pre-scaled): [b][h][s][d^swz]
          const int hh = n >> 6, d = n & 63;
          const size_t rb = (size_t)(b * 8 + hh) * 2048;
#pragma unroll
          for (int j = 0; j < 4; ++j)
            qsw[(rb + s + j) * 64 + (d ^ (((s + j) & 7) << 3))] = f2bf(vals[j] * C_QK);
        } else if (n < 1024) {                // K: same layout, unscaled
          const int hh = (n - 512) >> 6, d = (n - 512) & 63;
          const size_t rb = (size_t)(b * 8 + hh) * 2048;
#pragma unroll
          for (int j = 0; j < 4; ++j)
            ksw[(rb + s + j) * 64 + (d ^ (((s + j) & 7) << 3))] = f2bf(vals[j]);
        } else {                              // V: [b][h][d][s^swz]
          const int hh = (n - 1024) >> 6, d = (n - 1024) & 63;
          short4 pk = make_short4(f2bf(vals[0]), f2bf(vals[1]), f2bf(vals[2]), f2bf(vals[3]));
          *(short4*)&vsw[(size_t)((b * 8 + hh) * 64 + d) * 2048 + (s ^ ((d & 7) << 3))] = pk;
        }
      }
    }
  }
}

// ---------------------------------------------------------------- Attention v3
// 4 waves x 32 q-rows, KV tiles of 64, 32x32x16 MFMA, swapped QK^T, in-register
// softmax + defer-max + cvt_pk/permlane PV frags. v3: double-buffered K/V with
// prefetch-before-compute (T14/T3-min), one barrier per tile, setprio (T5).
__global__ __launch_bounds__(256)
void attn_mfma(const short* __restrict__ qsw, const short* __restrict__ ksw,
               const short* __restrict__ vsw, short* __restrict__ attn_o) {
  __shared__ short Qs[128 * 64] __attribute__((aligned(16)));
  __shared__ short Ks[2][64 * 64] __attribute__((aligned(16)));
  __shared__ short Vs[2][64 * 64] __attribute__((aligned(16)));
  const int t = threadIdx.x;
  const int w = t >> 6, l = t & 63;
  const int c = l & 31, hi = l >> 5;
  const int bh = blockIdx.y;
  const int q0 = blockIdx.x * 128;
  const short* qb = qsw + ((size_t)bh * 2048 + q0) * 64;
  const short* kb = ksw + (size_t)bh * 2048 * 64;
  const short* vb = vsw + (size_t)bh * 64 * 2048;

#define STAGE_KV(buf, kt)                                                       \
  {                                                                             \
    _Pragma("unroll")                                                           \
    for (int iss = 0; iss < 2; ++iss) {                                         \
      int q = iss * 256 + t;                                                    \
      gload16(kb + (size_t)((kt) + (q >> 3)) * 64 + (q & 7) * 8,                \
              (char*)Ks[buf] + q * 16);                                         \
    }                                                                           \
    _Pragma("unroll")                                                           \
    for (int iss = 0; iss < 2; ++iss) {                                         \
      int q = iss * 256 + t;                                                    \
      gload16(vb + (size_t)(q >> 3) * 2048 + (kt) + (q & 7) * 8,                \
              (char*)Vs[buf] + q * 16);                                         \
    }                                                                           \
  }

  // stage Q tile + first KV tile, one barrier
#pragma unroll
  for (int iss = 0; iss < 4; ++iss) {
    int q = iss * 256 + t;
    gload16(qb + (q >> 3) * 64 + (q & 7) * 8, (char*)Qs + q * 16);
  }
  STAGE_KV(0, 0);
  __syncthreads();

  const int qrow = w * 32 + c;
  const int swz = (c & 7) << 3;
  bf16x8 qf[4];
#pragma unroll
  for (int dc = 0; dc < 4; ++dc)
    qf[dc] = *(const bf16x8*)(Qs + qrow * 64 + ((dc * 16 + hi * 8) ^ swz));

  f32x16 o0 = {}, o1 = {};
  float m_run = -3e38f, l_run = 0.0f;

  for (int ti = 0; ti < 32; ++ti) {
    const int cur = ti & 1;
    if (ti < 31) STAGE_KV(cur ^ 1, (ti + 1) * 64);
    const short* Kc = Ks[cur];
    const short* Vc = Vs[cur];

    // S^T = K Q^T (scale pre-folded into Q)
    f32x16 s0 = {}, s1 = {};
    __builtin_amdgcn_s_setprio(1);
#pragma unroll
    for (int dc = 0; dc < 4; ++dc) {
      const int koff = (dc * 16 + hi * 8) ^ swz;
      bf16x8 kf0 = *(const bf16x8*)(Kc + c * 64 + koff);
      bf16x8 kf1 = *(const bf16x8*)(Kc + (32 + c) * 64 + koff);
      s0 = __builtin_amdgcn_mfma_f32_32x32x16_bf16(kf0, qf[dc], s0, 0, 0, 0);
      s1 = __builtin_amdgcn_mfma_f32_32x32x16_bf16(kf1, qf[dc], s1, 0, 0, 0);
    }
    __builtin_amdgcn_s_setprio(0);

    // in-lane softmax for q = w*32+c
    float tmax = -3e38f;
#pragma unroll
    for (int j = 0; j < 16; ++j) tmax = fmaxf(tmax, fmaxf(s0[j], s1[j]));
    tmax = fmaxf(tmax, __shfl_xor(tmax, 32, 64));
    if (__any(tmax - m_run > 8.0f)) {         // T13 defer-max (log2 domain)
      float mnew = fmaxf(m_run, tmax);
      float rs = __builtin_amdgcn_exp2f(m_run - mnew);
      m_run = mnew;
      l_run *= rs;
#pragma unroll
      for (int j = 0; j < 16; ++j) {
        float rj = __shfl(rs, (j & 3) + 8 * (j >> 2) + 4 * hi, 64);
        o0[j] *= rj; o1[j] *= rj;
      }
    }
    float rsum = 0.0f;
#pragma unroll
    for (int j = 0; j < 16; ++j) {
      s0[j] = __builtin_amdgcn_exp2f(s0[j] - m_run);
      s1[j] = __builtin_amdgcn_exp2f(s1[j] - m_run);
      rsum += s0[j] + s1[j];
    }
    rsum += __shfl_xor(rsum, 32, 64);
    l_run += rsum;

    // build PV A-frags (T12) and accumulate O
    __builtin_amdgcn_s_setprio(1);
#pragma unroll
    for (int kc = 0; kc < 4; ++kc) {
      const int jb = (kc & 1) * 8;
      int u0, u1, v0, v1;
      if (kc < 2) {
        asm("v_cvt_pk_bf16_f32 %0, %1, %2" : "=v"(u0) : "v"(s0[jb + 0]), "v"(s0[jb + 1]));
        asm("v_cvt_pk_bf16_f32 %0, %1, %2" : "=v"(u1) : "v"(s0[jb + 2]), "v"(s0[jb + 3]));
        asm("v_cvt_pk_bf16_f32 %0, %1, %2" : "=v"(v0) : "v"(s0[jb + 4]), "v"(s0[jb + 5]));
        asm("v_cvt_pk_bf16_f32 %0, %1, %2" : "=v"(v1) : "v"(s0[jb + 6]), "v"(s0[jb + 7]));
      } else {
        asm("v_cvt_pk_bf16_f32 %0, %1, %2" : "=v"(u0) : "v"(s1[jb + 0]), "v"(s1[jb + 1]));
        asm("v_cvt_pk_bf16_f32 %0, %1, %2" : "=v"(u1) : "v"(s1[jb + 2]), "v"(s1[jb + 3]));
        asm("v_cvt_pk_bf16_f32 %0, %1, %2" : "=v"(v0) : "v"(s1[jb + 4]), "v"(s1[jb + 5]));
        asm("v_cvt_pk_bf16_f32 %0, %1, %2" : "=v"(v1) : "v"(s1[jb + 6]), "v"(s1[jb + 7]));
      }
      asm volatile("v_permlane32_swap_b32 %0, %1" : "+v"(u0), "+v"(v0));
      asm volatile("v_permlane32_swap_b32 %0, %1" : "+v"(u1), "+v"(v1));
      int pw[4] = {u0, u1, v0, v1};
      bf16x8 pa = __builtin_bit_cast(bf16x8, *(int4*)pw);
      const int voff = (kc * 16 + hi * 8) ^ swz;
      bf16x8 vf0 = *(const bf16x8*)(Vc + c * 64 + voff);
      bf16x8 vf1 = *(const bf16x8*)(Vc + (32 + c) * 64 + voff);
      o0 = __builtin_amdgcn_mfma_f32_32x32x16_bf16(pa, vf0, o0, 0, 0, 0);
      o1 = __builtin_amdgcn_mfma_f32_32x32x16_bf16(pa, vf1, o1, 0, 0, 0);
    }
    __builtin_amdgcn_s_setprio(0);
    __syncthreads();                          // next-tile stage complete; cur free
  }
#undef STAGE_KV

  // finalize
  const int b = bh >> 3, hh = bh & 7;
  float inv = 1.0f / l_run;
#pragma unroll
  for (int j = 0; j < 16; ++j) {
    const int q_rel = (j & 3) + 8 * (j >> 2) + 4 * hi;
    float invq = __shfl(inv, q_rel, 64);
    const size_t row = (size_t)(b * 2048 + q0 + w * 32 + q_rel) * 512 + hh * 64;
    attn_o[row + c]      = f2bf(o0[j] * invq);
    attn_o[row + 32 + c] = f2bf(o1[j] * invq);
  }
}

// ---------------------------------------------------------------- Add + LayerNorm (fp32)
template<int WB>
__global__ __launch_bounds__(256)
void add_ln(const float* __restrict__ a, const float* __restrict__ res,
            const float* __restrict__ g_, const float* __restrict__ be,
            float* __restrict__ out, short* __restrict__ outb) {
  const int row = blockIdx.x;
  const int t = threadIdx.x;
  const size_t off = (size_t)row * D;
  float x0 = a[off + t] + res[off + t];
  float x1 = a[off + t + 256] + res[off + t + 256];
  float sum = x0 + x1;
  float sq  = x0 * x0 + x1 * x1;
#pragma unroll
  for (int o2 = 32; o2 > 0; o2 >>= 1) {
    sum += __shfl_down(sum, o2);
    sq  += __shfl_down(sq, o2);
  }
  __shared__ float ssum[4], ssq[4];
  const int wid = t >> 6;
  if ((t & 63) == 0) { ssum[wid] = sum; ssq[wid] = sq; }
  __syncthreads();
  if (t == 0) {
    ssum[0] = ssum[0] + ssum[1] + ssum[2] + ssum[3];
    ssq[0]  = ssq[0] + ssq[1] + ssq[2] + ssq[3];
  }
  __syncthreads();
  float mu   = ssum[0] * (1.0f / D);
  float var  = ssq[0] * (1.0f / D) - mu * mu;
  float rstd = rsqrtf(var + 1e-5f);
  float y0 = (x0 - mu) * rstd * g_[t] + be[t];
  float y1 = (x1 - mu) * rstd * g_[t + 256] + be[t + 256];
  out[off + t] = y0;
  out[off + t + 256] = y1;
  if (WB) {
    outb[off + t] = f2bf(y0);
    outb[off + t + 256] = f2bf(y1);
  }
}

// ---------------------------------------------------------------- launch
extern "C" void kernel_launch(void* const* d_in, const int* in_sizes, int n_in,
                              void* d_out, int out_size, void* d_ws, size_t ws_size,
                              hipStream_t stream) {
  const float* x     = (const float*)d_in[0];
  const float* w_qkv = (const float*)d_in[1];
  const float* b_qkv = (const float*)d_in[2];
  const float* w_o   = (const float*)d_in[3];
  const float* b_o   = (const float*)d_in[4];
  const float* w1    = (const float*)d_in[5];
  const float* b1    = (const float*)d_in[6];
  const float* w2    = (const float*)d_in[7];
  const float* b2    = (const float*)d_in[8];
  const float* g1    = (const float*)d_in[9];
  const float* be1   = (const float*)d_in[10];
  const float* g2    = (const float*)d_in[11];
  const float* be2   = (const float*)d_in[12];
  float* out = (float*)d_out;
  (void)in_sizes; (void)n_in; (void)out_size; (void)ws_size;

  const size_t MD = (size_t)M * 512;
  short* q_sw = (short*)d_ws;           // [B][H][S][64] swz (pre-scaled)
  short* k_sw = q_sw + MD;
  short* v_sw = k_sw + MD;              // [B][H][64][S] swz
  short* a_o  = v_sw + MD;              // attn out [M][512]
  short* h    = q_sw;                   // FFN hidden overlays q/k/v/a_o (dead)
  short* xb   = a_o + MD;
  short* ln1b = xb;                     // ln1 bf16 overlays xb (dead after GEMM1)
  short* wtq  = xb + MD;
  short* wto  = wtq + (size_t)1536 * 512;
  short* wt1  = wto + (size_t)512 * 512;
  short* wt2  = wt1 + (size_t)512 * 2048;
  float* buf  = (float*)(wt2 + (size_t)2048 * 512);
  float* ln1  = buf + MD;

  prep_all<<<7168, 256, 0, stream>>>(x, xb, w_qkv, wtq, w_o, wto, w1, wt1, w2, wt2);

  gemm_bf16<0, 2><<<dim3(12, 64), 256, 0, stream>>>(
      xb, wtq, b_qkv, nullptr, nullptr, q_sw, k_sw, v_sw, 512, 1536);
  attn_mfma<<<dim3(16, 32), 256, 0, stream>>>(q_sw, k_sw, v_sw, a_o);
  gemm_bf16<0, 0><<<dim3(4, 64), 256, 0, stream>>>(
      a_o, wto, b_o, buf, nullptr, nullptr, nullptr, nullptr, 512, 512);
  add_ln<1><<<M, 256, 0, stream>>>(buf, x, g1, be1, ln1, ln1b);
  gemm_bf16<1, 1><<<dim3(16, 64), 256, 0, stream>>>(
      ln1b, wt1, b1, nullptr, h, nullptr, nullptr, nullptr, 512, 2048);
  gemm_bf16<0, 0><<<dim3(4, 64), 256, 0, stream>>>(
      h, wt2, b2, buf, nullptr, nullptr, nullptr, nullptr, 2048, 512);
  add_ln<0><<<M, 256, 0, stream>>>(buf, ln1, g2, be2, out, nullptr);
}